// Round 1
// baseline (941.450 us; speedup 1.0000x reference)
//
#include <hip/hip_runtime.h>

#define N_NODES 50000
#define N_EDGES 600000
#define DD 128
#define N_LAYERS 6

// ---------------- CSR build ----------------

__global__ void zero_counts(int* __restrict__ deg, int* __restrict__ cursor) {
    int i = blockIdx.x * blockDim.x + threadIdx.x;
    if (i < N_NODES) { deg[i] = 0; cursor[i] = 0; }
}

__global__ void count_deg(const int* __restrict__ dst, int* __restrict__ deg) {
    int e = blockIdx.x * blockDim.x + threadIdx.x;
    if (e < N_EDGES) atomicAdd(&deg[dst[e]], 1);
}

// single-block exclusive scan over 50000 degrees + deg_inv
__global__ void scan_offsets(const int* __restrict__ deg, int* __restrict__ offsets,
                             float* __restrict__ deg_inv) {
    __shared__ int s[1024];
    int tid = threadIdx.x;
    int carry = 0;
    for (int base = 0; base < N_NODES; base += 1024) {
        int i = base + tid;
        int v = (i < N_NODES) ? deg[i] : 0;
        if (i < N_NODES) deg_inv[i] = 1.0f / (float)((v > 1) ? v : 1);
        s[tid] = v;
        __syncthreads();
        #pragma unroll
        for (int off = 1; off < 1024; off <<= 1) {
            int t = (tid >= off) ? s[tid - off] : 0;
            __syncthreads();
            s[tid] += t;
            __syncthreads();
        }
        if (i < N_NODES) offsets[i] = carry + s[tid] - v;  // exclusive
        int total = s[1023];
        __syncthreads();   // everyone read s[1023] before next iteration overwrites
        carry += total;
    }
    if (tid == 0) offsets[N_NODES] = carry;
}

__global__ void fill_csr(const int* __restrict__ src, const int* __restrict__ dst,
                         const int* __restrict__ offsets, int* __restrict__ cursor,
                         int* __restrict__ csr_src) {
    int e = blockIdx.x * blockDim.x + threadIdx.x;
    if (e < N_EDGES) {
        int d = dst[e];
        int p = atomicAdd(&cursor[d], 1);
        csr_src[offsets[d] + p] = src[e];
    }
}

// ---------------- per-layer: mean aggregation (wave per node) ----------------

__global__ void aggregate(const float* __restrict__ hin, const int* __restrict__ offsets,
                          const int* __restrict__ csr_src, const float* __restrict__ deg_inv,
                          float* __restrict__ agg) {
    int wid  = threadIdx.x >> 6;
    int lane = threadIdx.x & 63;
    int node = blockIdx.x * 4 + wid;
    if (node >= N_NODES) return;
    int s = offsets[node], e = offsets[node + 1];
    float ax = 0.f, ay = 0.f;
    for (int j = s; j < e; ++j) {
        int src = csr_src[j];
        float2 v = ((const float2*)(hin + (size_t)src * DD))[lane];
        ax += v.x; ay += v.y;
    }
    float di = deg_inv[node];
    float2 o; o.x = ax * di; o.y = ay * di;
    ((float2*)(agg + (size_t)node * DD))[lane] = o;
}

// ---------------- per-layer: fused h' = relu(A@Wl + B@Wr + bl) ----------------
// Block tile: 128 nodes x 128 cols, 256 threads, 8x8 micro-tile per thread.

__launch_bounds__(256)
__global__ void gemm_fused(const float* __restrict__ A, const float* __restrict__ B,
                           const float* __restrict__ Wl, const float* __restrict__ Wr,
                           const float* __restrict__ bias, float* __restrict__ C) {
    __shared__ float sA[128][33];   // stride 33: odd stride -> row-bank spread
    __shared__ float sW[32][128];

    int tid = threadIdx.x;
    int n0  = blockIdx.x * 128;
    int tx  = tid & 15;   // cols tx*8 .. tx*8+7
    int ty  = tid >> 4;   // rows ty*8 .. ty*8+7

    float4 acc0[8], acc1[8];
    #pragma unroll
    for (int r = 0; r < 8; ++r) {
        acc0[r] = make_float4(0.f, 0.f, 0.f, 0.f);
        acc1[r] = make_float4(0.f, 0.f, 0.f, 0.f);
    }

    for (int m = 0; m < 2; ++m) {
        const float* X = m ? B : A;
        const float* W = m ? Wr : Wl;
        for (int k0 = 0; k0 < DD; k0 += 32) {
            // stage A tile: 128 rows x 32 k
            #pragma unroll
            for (int t = 0; t < 4; ++t) {
                int i   = tid + t * 256;       // [0,1024)
                int row = i >> 3;
                int c4  = (i & 7) * 4;
                int gr  = n0 + row; if (gr > N_NODES - 1) gr = N_NODES - 1;
                float4 v = *(const float4*)(X + (size_t)gr * DD + k0 + c4);
                sA[row][c4 + 0] = v.x; sA[row][c4 + 1] = v.y;
                sA[row][c4 + 2] = v.z; sA[row][c4 + 3] = v.w;
            }
            // stage W tile: 32 k x 128 cols
            #pragma unroll
            for (int t = 0; t < 4; ++t) {
                int i   = tid + t * 256;       // [0,1024)
                int row = i >> 5;
                int c4  = (i & 31) * 4;
                float4 v = *(const float4*)(W + (size_t)(k0 + row) * DD + c4);
                *(float4*)&sW[row][c4] = v;
            }
            __syncthreads();
            #pragma unroll
            for (int kk = 0; kk < 32; ++kk) {
                float4 w0 = *(const float4*)&sW[kk][tx * 8];
                float4 w1 = *(const float4*)&sW[kk][tx * 8 + 4];
                #pragma unroll
                for (int r = 0; r < 8; ++r) {
                    float a = sA[ty * 8 + r][kk];
                    acc0[r].x += a * w0.x; acc0[r].y += a * w0.y;
                    acc0[r].z += a * w0.z; acc0[r].w += a * w0.w;
                    acc1[r].x += a * w1.x; acc1[r].y += a * w1.y;
                    acc1[r].z += a * w1.z; acc1[r].w += a * w1.w;
                }
            }
            __syncthreads();
        }
    }

    float4 b0 = *(const float4*)(bias + tx * 8);
    float4 b1 = *(const float4*)(bias + tx * 8 + 4);
    #pragma unroll
    for (int r = 0; r < 8; ++r) {
        int gr = n0 + ty * 8 + r;
        if (gr < N_NODES) {
            float4 o0, o1;
            o0.x = fmaxf(acc0[r].x + b0.x, 0.f);
            o0.y = fmaxf(acc0[r].y + b0.y, 0.f);
            o0.z = fmaxf(acc0[r].z + b0.z, 0.f);
            o0.w = fmaxf(acc0[r].w + b0.w, 0.f);
            o1.x = fmaxf(acc1[r].x + b1.x, 0.f);
            o1.y = fmaxf(acc1[r].y + b1.y, 0.f);
            o1.z = fmaxf(acc1[r].z + b1.z, 0.f);
            o1.w = fmaxf(acc1[r].w + b1.w, 0.f);
            *(float4*)(C + (size_t)gr * DD + tx * 8)     = o0;
            *(float4*)(C + (size_t)gr * DD + tx * 8 + 4) = o1;
        }
    }
}

// ---------------- final FC: out = h @ fc_W + fc_b, OUT=2 ----------------

__global__ void fc_kernel(const float* __restrict__ h, const float* __restrict__ fcW,
                          const float* __restrict__ fcb, float* __restrict__ out) {
    int i = blockIdx.x * blockDim.x + threadIdx.x;  // over N_NODES*2
    if (i < N_NODES * 2) {
        int n = i >> 1, o = i & 1;
        const float* hr = h + (size_t)n * DD;
        float s = fcb[o];
        #pragma unroll 8
        for (int k = 0; k < DD; ++k) s += hr[k] * fcW[k * 2 + o];
        out[i] = s;
    }
}

// ---------------- launch ----------------

extern "C" void kernel_launch(void* const* d_in, const int* in_sizes, int n_in,
                              void* d_out, int out_size, void* d_ws, size_t ws_size,
                              hipStream_t stream) {
    const float* x    = (const float*)d_in[0];
    const int*   ei   = (const int*)d_in[1];
    const float* Wl   = (const float*)d_in[2];
    const float* Wr   = (const float*)d_in[3];
    const float* bl   = (const float*)d_in[4];
    const float* fcW  = (const float*)d_in[5];
    const float* fcb  = (const float*)d_in[6];
    float* out = (float*)d_out;

    const int* srcIdx = ei;
    const int* dstIdx = ei + N_EDGES;

    char* ws = (char*)d_ws;
    size_t off = 0;
    auto bump = [&](size_t bytes) { char* p = ws + off; off = (off + bytes + 255) & ~(size_t)255; return p; };
    int*   deg     = (int*)  bump(N_NODES * 4);
    int*   cursor  = (int*)  bump(N_NODES * 4);
    int*   offsets = (int*)  bump((N_NODES + 1) * 4);
    float* deg_inv = (float*)bump(N_NODES * 4);
    int*   csr     = (int*)  bump(N_EDGES * 4);
    float* h0      = (float*)bump((size_t)N_NODES * DD * 4);
    float* h1      = (float*)bump((size_t)N_NODES * DD * 4);
    float* agg     = (float*)bump((size_t)N_NODES * DD * 4);
    (void)ws_size;

    zero_counts<<<(N_NODES + 255) / 256, 256, 0, stream>>>(deg, cursor);
    count_deg<<<(N_EDGES + 255) / 256, 256, 0, stream>>>(dstIdx, deg);
    scan_offsets<<<1, 1024, 0, stream>>>(deg, offsets, deg_inv);
    fill_csr<<<(N_EDGES + 255) / 256, 256, 0, stream>>>(srcIdx, dstIdx, offsets, cursor, csr);

    const float* hin = x;
    float* hbuf[2] = { h0, h1 };
    for (int l = 0; l < N_LAYERS; ++l) {
        aggregate<<<(N_NODES + 3) / 4, 256, 0, stream>>>(hin, offsets, csr, deg_inv, agg);
        float* hout = hbuf[l & 1];
        gemm_fused<<<(N_NODES + 127) / 128, 256, 0, stream>>>(
            agg, hin, Wl + (size_t)l * DD * DD, Wr + (size_t)l * DD * DD, bl + (size_t)l * DD, hout);
        hin = hout;
    }
    fc_kernel<<<(N_NODES * 2 + 255) / 256, 256, 0, stream>>>(hin, fcW, fcb, out);
}

// Round 2
// 704.794 us; speedup vs baseline: 1.3358x; 1.3358x over previous
//
#include <hip/hip_runtime.h>
#include <hip/hip_bf16.h>

#define N_NODES 50000
#define N_EDGES 600000
#define DD 128
#define N_LAYERS 6

typedef __attribute__((ext_vector_type(8))) short bf16x8;
typedef __attribute__((ext_vector_type(4))) float floatx4;

__device__ __forceinline__ void ldsdma16(const void* g, void* l) {
    __builtin_amdgcn_global_load_lds(
        (const __attribute__((address_space(1))) char*)g,
        (__attribute__((address_space(3))) char*)l, 16, 0, 0);
}

__device__ __forceinline__ unsigned short f2b(float f) {
    unsigned u = __float_as_uint(f);
    unsigned r = (u + 0x7FFFu + ((u >> 16) & 1u)) >> 16;
    return (unsigned short)r;
}
__device__ __forceinline__ float b2f(unsigned short b) {
    return __uint_as_float(((unsigned)b) << 16);
}

// ---------------- CSR build ----------------

__global__ void zero_counts(int* __restrict__ deg, int* __restrict__ cursor) {
    int i = blockIdx.x * blockDim.x + threadIdx.x;
    if (i < N_NODES) { deg[i] = 0; cursor[i] = 0; }
}

__global__ void count_deg(const int* __restrict__ dst, int* __restrict__ deg) {
    int e = blockIdx.x * blockDim.x + threadIdx.x;
    if (e < N_EDGES) atomicAdd(&deg[dst[e]], 1);
}

// chunked single-block scan: each thread owns 49 consecutive nodes
__global__ void scan_offsets(const int* __restrict__ deg, int* __restrict__ offsets,
                             float* __restrict__ deg_inv) {
    __shared__ int s[1024];
    const int CH = 49;   // 1024*49 = 50176 >= 50000
    int tid = threadIdx.x;
    int base = tid * CH;
    int sum = 0;
    for (int i = 0; i < CH; ++i) {
        int g = base + i;
        if (g < N_NODES) sum += deg[g];
    }
    s[tid] = sum;
    __syncthreads();
    for (int off = 1; off < 1024; off <<= 1) {
        int t = (tid >= off) ? s[tid - off] : 0;
        __syncthreads();
        s[tid] += t;
        __syncthreads();
    }
    int run = s[tid] - sum;  // exclusive prefix for this chunk
    for (int i = 0; i < CH; ++i) {
        int g = base + i;
        if (g < N_NODES) {
            int d = deg[g];
            offsets[g] = run;
            run += d;
            deg_inv[g] = 1.0f / (float)(d > 1 ? d : 1);
        }
    }
    if (tid == 1023) offsets[N_NODES] = s[1023];
}

__global__ void fill_csr(const int* __restrict__ src, const int* __restrict__ dst,
                         const int* __restrict__ offsets, int* __restrict__ cursor,
                         int* __restrict__ csr_src) {
    int e = blockIdx.x * blockDim.x + threadIdx.x;
    if (e < N_EDGES) {
        int d = dst[e];
        int p = atomicAdd(&cursor[d], 1);
        csr_src[offsets[d] + p] = src[e];
    }
}

// ---------------- dtype prep ----------------

__global__ void x_to_bf16(const float* __restrict__ x, unsigned short* __restrict__ hx) {
    int idx = blockIdx.x * blockDim.x + threadIdx.x;   // over 1.6M
    int b = idx * 4;
    float4 v = *(const float4*)(x + b);
    ushort4 o;
    o.x = f2b(v.x); o.y = f2b(v.y); o.z = f2b(v.z); o.w = f2b(v.w);
    *(ushort4*)(hx + b) = o;
}

// WT2[l][n][k2]: k2<128 -> Wl[l][k2][n], else Wr[l][k2-128][n]   (bf16)
__global__ void prep_weights(const float* __restrict__ Wl, const float* __restrict__ Wr,
                             unsigned short* __restrict__ WT2) {
    int idx = blockIdx.x * blockDim.x + threadIdx.x;  // 6*128*256 = 196608
    int l   = idx >> 15;          // /32768
    int rem = idx & 32767;
    int n   = rem >> 8;
    int k2  = rem & 255;
    const float* W = (k2 < 128 ? Wl : Wr) + (size_t)l * DD * DD + (size_t)(k2 & 127) * DD + n;
    WT2[idx] = f2b(*W);
}

// ---------------- mean aggregation (wave per node, bf16) ----------------

__global__ void aggregate(const unsigned short* __restrict__ hin, const int* __restrict__ offsets,
                          const int* __restrict__ csr_src, const float* __restrict__ deg_inv,
                          unsigned short* __restrict__ agg) {
    int wid  = threadIdx.x >> 6;
    int lane = threadIdx.x & 63;
    int node = blockIdx.x * 4 + wid;
    if (node >= N_NODES) return;
    int s = offsets[node], e = offsets[node + 1];
    float ax = 0.f, ay = 0.f;
    for (int j = s; j < e; ++j) {
        int src = csr_src[j];
        unsigned v = ((const unsigned*)(hin + (size_t)src * DD))[lane];
        ax += __uint_as_float(v << 16);
        ay += __uint_as_float(v & 0xFFFF0000u);
    }
    float di = deg_inv[node];
    ushort2 o; o.x = f2b(ax * di); o.y = f2b(ay * di);
    ((ushort2*)(agg + (size_t)node * DD))[lane] = o;
}

// ---------------- fused MFMA GEMM: C = relu([Agg|H] @ [Wl;Wr] + b) ----------------
// 128x128 tile, 256 threads = 4 waves in 2x2, each wave 64x64 (4x4 of 16x16x32 MFMA).

__launch_bounds__(256)
__global__ void gemm_mfma(const unsigned short* __restrict__ Agg,
                          const unsigned short* __restrict__ H,
                          const unsigned short* __restrict__ WT2,   // [128 n][256 k]
                          const float* __restrict__ bias,
                          unsigned short* __restrict__ Cout) {
    __shared__ unsigned short sA[128 * 32];
    __shared__ unsigned short sW[128 * 32];

    int tid  = threadIdx.x;
    int lane = tid & 63, wid = tid >> 6;
    int wm = wid >> 1, wn = wid & 1;
    int n0 = blockIdx.x * 128;

    floatx4 acc[4][4];
    #pragma unroll
    for (int i = 0; i < 4; ++i)
        #pragma unroll
        for (int j = 0; j < 4; ++j)
            acc[i][j] = (floatx4){0.f, 0.f, 0.f, 0.f};

    // staging chunk geometry (swizzled): chunk c holds (row=c>>2, quad=(c&3)^((row>>1)&3))
    int c0 = tid, c1 = tid + 256;
    int rA0 = c0 >> 2, qA0 = (c0 & 3) ^ ((rA0 >> 1) & 3);
    int rA1 = c1 >> 2, qA1 = (c1 & 3) ^ ((rA1 >> 1) & 3);
    int gr0 = n0 + rA0; if (gr0 > N_NODES - 1) gr0 = N_NODES - 1;
    int gr1 = n0 + rA1; if (gr1 > N_NODES - 1) gr1 = N_NODES - 1;

    int l15 = lane & 15, q = lane >> 4;

    #pragma unroll
    for (int half = 0; half < 2; ++half) {
        const unsigned short* X = half ? H : Agg;
        #pragma unroll
        for (int kk = 0; kk < 4; ++kk) {
            int k0 = kk * 32;
            int k2 = half * 128 + k0;
            ldsdma16(X + (size_t)gr0 * DD + k0 + qA0 * 8, sA + c0 * 8);
            ldsdma16(X + (size_t)gr1 * DD + k0 + qA1 * 8, sA + c1 * 8);
            ldsdma16(WT2 + (size_t)rA0 * 256 + k2 + qA0 * 8, sW + c0 * 8);
            ldsdma16(WT2 + (size_t)rA1 * 256 + k2 + qA1 * 8, sW + c1 * 8);
            __syncthreads();

            bf16x8 aF[4], bF[4];
            #pragma unroll
            for (int i = 0; i < 4; ++i) {
                int row = wm * 64 + i * 16 + l15;
                int ca  = row * 4 + (q ^ ((row >> 1) & 3));
                aF[i] = *(const bf16x8*)(sA + ca * 8);
                int nn = wn * 64 + i * 16 + l15;
                int cb = nn * 4 + (q ^ ((nn >> 1) & 3));
                bF[i] = *(const bf16x8*)(sW + cb * 8);
            }
            #pragma unroll
            for (int i = 0; i < 4; ++i)
                #pragma unroll
                for (int j = 0; j < 4; ++j)
                    acc[i][j] = __builtin_amdgcn_mfma_f32_16x16x32_bf16(aF[i], bF[j], acc[i][j], 0, 0, 0);
            __syncthreads();
        }
    }

    // epilogue: C row = quad*4+reg, col = lane&15
    float bcol[4];
    #pragma unroll
    for (int j = 0; j < 4; ++j) bcol[j] = bias[wn * 64 + j * 16 + l15];
    #pragma unroll
    for (int i = 0; i < 4; ++i) {
        #pragma unroll
        for (int r = 0; r < 4; ++r) {
            int row = n0 + wm * 64 + i * 16 + q * 4 + r;
            if (row < N_NODES) {
                #pragma unroll
                for (int j = 0; j < 4; ++j) {
                    int col = wn * 64 + j * 16 + l15;
                    float v = acc[i][j][r] + bcol[j];
                    v = fmaxf(v, 0.f);
                    Cout[(size_t)row * DD + col] = f2b(v);
                }
            }
        }
    }
}

// ---------------- final FC: out = h @ fc_W + fc_b ----------------

__global__ void fc_kernel(const unsigned short* __restrict__ h, const float* __restrict__ fcW,
                          const float* __restrict__ fcb, float* __restrict__ out) {
    int n = blockIdx.x * blockDim.x + threadIdx.x;
    if (n >= N_NODES) return;
    const unsigned* hr = (const unsigned*)(h + (size_t)n * DD);
    float s0 = fcb[0], s1 = fcb[1];
    #pragma unroll 8
    for (int k = 0; k < 64; ++k) {
        unsigned v = hr[k];
        float h0 = __uint_as_float(v << 16);
        float h1 = __uint_as_float(v & 0xFFFF0000u);
        s0 += h0 * fcW[(2 * k) * 2]     + h1 * fcW[(2 * k + 1) * 2];
        s1 += h0 * fcW[(2 * k) * 2 + 1] + h1 * fcW[(2 * k + 1) * 2 + 1];
    }
    out[n * 2] = s0; out[n * 2 + 1] = s1;
}

// ---------------- launch ----------------

extern "C" void kernel_launch(void* const* d_in, const int* in_sizes, int n_in,
                              void* d_out, int out_size, void* d_ws, size_t ws_size,
                              hipStream_t stream) {
    const float* x    = (const float*)d_in[0];
    const int*   ei   = (const int*)d_in[1];
    const float* Wl   = (const float*)d_in[2];
    const float* Wr   = (const float*)d_in[3];
    const float* bl   = (const float*)d_in[4];
    const float* fcW  = (const float*)d_in[5];
    const float* fcb  = (const float*)d_in[6];
    float* out = (float*)d_out;

    const int* srcIdx = ei;
    const int* dstIdx = ei + N_EDGES;

    char* ws = (char*)d_ws;
    size_t off = 0;
    auto bump = [&](size_t bytes) { char* p = ws + off; off = (off + bytes + 255) & ~(size_t)255; return p; };
    int*   deg     = (int*)  bump(N_NODES * 4);
    int*   cursor  = (int*)  bump(N_NODES * 4);
    int*   offsets = (int*)  bump((N_NODES + 1) * 4);
    float* deg_inv = (float*)bump(N_NODES * 4);
    int*   csr     = (int*)  bump(N_EDGES * 4);
    unsigned short* hx   = (unsigned short*)bump((size_t)N_NODES * DD * 2);
    unsigned short* hb0  = (unsigned short*)bump((size_t)N_NODES * DD * 2);
    unsigned short* hb1  = (unsigned short*)bump((size_t)N_NODES * DD * 2);
    unsigned short* agg  = (unsigned short*)bump((size_t)N_NODES * DD * 2);
    unsigned short* WT2  = (unsigned short*)bump((size_t)N_LAYERS * 128 * 256 * 2);
    (void)ws_size;

    zero_counts<<<(N_NODES + 255) / 256, 256, 0, stream>>>(deg, cursor);
    count_deg<<<(N_EDGES + 255) / 256, 256, 0, stream>>>(dstIdx, deg);
    scan_offsets<<<1, 1024, 0, stream>>>(deg, offsets, deg_inv);
    fill_csr<<<(N_EDGES + 255) / 256, 256, 0, stream>>>(srcIdx, dstIdx, offsets, cursor, csr);
    x_to_bf16<<<(N_NODES * DD / 4 + 255) / 256, 256, 0, stream>>>(x, hx);
    prep_weights<<<(N_LAYERS * 128 * 256 + 255) / 256, 256, 0, stream>>>(Wl, Wr, WT2);

    const unsigned short* hin = hx;
    unsigned short* hbuf[2] = { hb0, hb1 };
    for (int l = 0; l < N_LAYERS; ++l) {
        aggregate<<<(N_NODES + 3) / 4, 256, 0, stream>>>(hin, offsets, csr, deg_inv, agg);
        unsigned short* hout = hbuf[l & 1];
        gemm_mfma<<<(N_NODES + 127) / 128, 256, 0, stream>>>(
            agg, hin, WT2 + (size_t)l * 128 * 256, bl + (size_t)l * DD, hout);
        hin = hout;
    }
    fc_kernel<<<(N_NODES + 255) / 256, 256, 0, stream>>>(hin, fcW, fcb, out);
}

// Round 3
// 402.272 us; speedup vs baseline: 2.3403x; 1.7520x over previous
//
#include <hip/hip_runtime.h>
#include <hip/hip_bf16.h>

#define N_NODES 50000
#define N_EDGES 600000
#define DD 128
#define N_LAYERS 6
#define SCAN_BLOCKS 196   // ceil(50000/256)

typedef __attribute__((ext_vector_type(8))) short bf16x8;
typedef __attribute__((ext_vector_type(4))) float floatx4;

__device__ __forceinline__ void ldsdma16(const void* g, void* l) {
    __builtin_amdgcn_global_load_lds(
        (const __attribute__((address_space(1))) char*)g,
        (__attribute__((address_space(3))) char*)l, 16, 0, 0);
}

__device__ __forceinline__ unsigned short f2b(float f) {
    unsigned u = __float_as_uint(f);
    unsigned r = (u + 0x7FFFu + ((u >> 16) & 1u)) >> 16;
    return (unsigned short)r;
}

// ---------------- CSR build ----------------

__global__ void zero_counts(int* __restrict__ deg, int* __restrict__ cursor) {
    int i = blockIdx.x * blockDim.x + threadIdx.x;
    if (i < N_NODES) { deg[i] = 0; cursor[i] = 0; }
}

__global__ void count_deg(const int* __restrict__ dst, int* __restrict__ deg) {
    int e = blockIdx.x * blockDim.x + threadIdx.x;
    if (e < N_EDGES) atomicAdd(&deg[dst[e]], 1);
}

// phase 1: per-block sums of 256 degrees
__global__ void block_sums(const int* __restrict__ deg, int* __restrict__ bsum) {
    __shared__ int s[256];
    int tid = threadIdx.x;
    int i = blockIdx.x * 256 + tid;
    int v = (i < N_NODES) ? deg[i] : 0;
    s[tid] = v;
    __syncthreads();
    #pragma unroll
    for (int off = 128; off > 0; off >>= 1) {
        if (tid < off) s[tid] += s[tid + off];
        __syncthreads();
    }
    if (tid == 0) bsum[blockIdx.x] = s[0];
}

// phase 2: exclusive scan of 196 block sums (single small block)
__global__ void scan_bsums(int* __restrict__ bsum, int* __restrict__ offsets) {
    __shared__ int s[256];
    int tid = threadIdx.x;
    int v = (tid < SCAN_BLOCKS) ? bsum[tid] : 0;
    s[tid] = v;
    __syncthreads();
    for (int off = 1; off < 256; off <<= 1) {
        int t = (tid >= off) ? s[tid - off] : 0;
        __syncthreads();
        s[tid] += t;
        __syncthreads();
    }
    if (tid < SCAN_BLOCKS) bsum[tid] = s[tid] - v;   // exclusive
    if (tid == 0) offsets[N_NODES] = N_EDGES;
}

// phase 3: intra-block scan + add block base; also deg_inv
__global__ void write_offsets(const int* __restrict__ deg, const int* __restrict__ bsum,
                              int* __restrict__ offsets, float* __restrict__ deg_inv) {
    __shared__ int s[256];
    int tid = threadIdx.x;
    int i = blockIdx.x * 256 + tid;
    int v = (i < N_NODES) ? deg[i] : 0;
    s[tid] = v;
    __syncthreads();
    for (int off = 1; off < 256; off <<= 1) {
        int t = (tid >= off) ? s[tid - off] : 0;
        __syncthreads();
        s[tid] += t;
        __syncthreads();
    }
    if (i < N_NODES) {
        offsets[i] = bsum[blockIdx.x] + s[tid] - v;
        deg_inv[i] = 1.0f / (float)(v > 1 ? v : 1);
    }
}

__global__ void fill_csr(const int* __restrict__ src, const int* __restrict__ dst,
                         const int* __restrict__ offsets, int* __restrict__ cursor,
                         int* __restrict__ csr_src) {
    int e = blockIdx.x * blockDim.x + threadIdx.x;
    if (e < N_EDGES) {
        int d = dst[e];
        int p = atomicAdd(&cursor[d], 1);
        csr_src[offsets[d] + p] = src[e];
    }
}

// ---------------- dtype prep ----------------

__global__ void x_to_bf16(const float* __restrict__ x, unsigned short* __restrict__ hx) {
    int idx = blockIdx.x * blockDim.x + threadIdx.x;   // over 1.6M
    int b = idx * 4;
    float4 v = *(const float4*)(x + b);
    ushort4 o;
    o.x = f2b(v.x); o.y = f2b(v.y); o.z = f2b(v.z); o.w = f2b(v.w);
    *(ushort4*)(hx + b) = o;
}

// WT2[l][n][k2]: k2<128 -> Wl[l][k2][n], else Wr[l][k2-128][n]   (bf16)
__global__ void prep_weights(const float* __restrict__ Wl, const float* __restrict__ Wr,
                             unsigned short* __restrict__ WT2) {
    int idx = blockIdx.x * blockDim.x + threadIdx.x;  // 6*128*256 = 196608
    int l   = idx >> 15;
    int rem = idx & 32767;
    int n   = rem >> 8;
    int k2  = rem & 255;
    const float* W = (k2 < 128 ? Wl : Wr) + (size_t)l * DD * DD + (size_t)(k2 & 127) * DD + n;
    WT2[idx] = f2b(*W);
}

// ---------------- mean aggregation (wave per node, 4 edges in flight) ----------------

__global__ void aggregate(const unsigned short* __restrict__ hin, const int* __restrict__ offsets,
                          const int* __restrict__ csr_src, const float* __restrict__ deg_inv,
                          unsigned short* __restrict__ agg) {
    int wid  = threadIdx.x >> 6;
    int lane = threadIdx.x & 63;
    int grp  = lane >> 4;      // 0..3: which edge slot
    int l16  = lane & 15;      // feature chunk: 8 bf16 at l16*8
    int node = blockIdx.x * 4 + wid;
    if (node >= N_NODES) return;
    int s = offsets[node], e = offsets[node + 1];

    float a0=0,a1=0,a2=0,a3=0,a4=0,a5=0,a6=0,a7=0;
    for (int j = s + grp; j < e; j += 4) {
        int src = csr_src[j];
        uint4 v = *(const uint4*)(hin + (size_t)src * DD + l16 * 8);
        a0 += __uint_as_float(v.x << 16); a1 += __uint_as_float(v.x & 0xFFFF0000u);
        a2 += __uint_as_float(v.y << 16); a3 += __uint_as_float(v.y & 0xFFFF0000u);
        a4 += __uint_as_float(v.z << 16); a5 += __uint_as_float(v.z & 0xFFFF0000u);
        a6 += __uint_as_float(v.w << 16); a7 += __uint_as_float(v.w & 0xFFFF0000u);
    }
    // reduce across the 4 groups (same l16, different grp): xor 16 then 32
    a0 += __shfl_xor(a0, 16, 64); a1 += __shfl_xor(a1, 16, 64);
    a2 += __shfl_xor(a2, 16, 64); a3 += __shfl_xor(a3, 16, 64);
    a4 += __shfl_xor(a4, 16, 64); a5 += __shfl_xor(a5, 16, 64);
    a6 += __shfl_xor(a6, 16, 64); a7 += __shfl_xor(a7, 16, 64);
    a0 += __shfl_xor(a0, 32, 64); a1 += __shfl_xor(a1, 32, 64);
    a2 += __shfl_xor(a2, 32, 64); a3 += __shfl_xor(a3, 32, 64);
    a4 += __shfl_xor(a4, 32, 64); a5 += __shfl_xor(a5, 32, 64);
    a6 += __shfl_xor(a6, 32, 64); a7 += __shfl_xor(a7, 32, 64);

    if (grp == 0) {
        float di = deg_inv[node];
        uint4 o;
        o.x = (unsigned)f2b(a0 * di) | ((unsigned)f2b(a1 * di) << 16);
        o.y = (unsigned)f2b(a2 * di) | ((unsigned)f2b(a3 * di) << 16);
        o.z = (unsigned)f2b(a4 * di) | ((unsigned)f2b(a5 * di) << 16);
        o.w = (unsigned)f2b(a6 * di) | ((unsigned)f2b(a7 * di) << 16);
        *(uint4*)(agg + (size_t)node * DD + l16 * 8) = o;
    }
}

// ---------------- fused MFMA GEMM: C = relu([Agg|H] @ [Wl;Wr] + b) ----------------
// 128x128 tile, 256 threads = 4 waves in 2x2, each wave 64x64 (4x4 of 16x16x32 MFMA).

__launch_bounds__(256)
__global__ void gemm_mfma(const unsigned short* __restrict__ Agg,
                          const unsigned short* __restrict__ H,
                          const unsigned short* __restrict__ WT2,   // [128 n][256 k]
                          const float* __restrict__ bias,
                          unsigned short* __restrict__ Cout) {
    __shared__ unsigned short sA[128 * 32];
    __shared__ unsigned short sW[128 * 32];

    int tid  = threadIdx.x;
    int lane = tid & 63, wid = tid >> 6;
    int wm = wid >> 1, wn = wid & 1;
    int n0 = blockIdx.x * 128;

    floatx4 acc[4][4];
    #pragma unroll
    for (int i = 0; i < 4; ++i)
        #pragma unroll
        for (int j = 0; j < 4; ++j)
            acc[i][j] = (floatx4){0.f, 0.f, 0.f, 0.f};

    int c0 = tid, c1 = tid + 256;
    int rA0 = c0 >> 2, qA0 = (c0 & 3) ^ ((rA0 >> 1) & 3);
    int rA1 = c1 >> 2, qA1 = (c1 & 3) ^ ((rA1 >> 1) & 3);
    int gr0 = n0 + rA0; if (gr0 > N_NODES - 1) gr0 = N_NODES - 1;
    int gr1 = n0 + rA1; if (gr1 > N_NODES - 1) gr1 = N_NODES - 1;

    int l15 = lane & 15, q = lane >> 4;

    #pragma unroll
    for (int half = 0; half < 2; ++half) {
        const unsigned short* X = half ? H : Agg;
        #pragma unroll
        for (int kk = 0; kk < 4; ++kk) {
            int k0 = kk * 32;
            int k2 = half * 128 + k0;
            ldsdma16(X + (size_t)gr0 * DD + k0 + qA0 * 8, sA + c0 * 8);
            ldsdma16(X + (size_t)gr1 * DD + k0 + qA1 * 8, sA + c1 * 8);
            ldsdma16(WT2 + (size_t)rA0 * 256 + k2 + qA0 * 8, sW + c0 * 8);
            ldsdma16(WT2 + (size_t)rA1 * 256 + k2 + qA1 * 8, sW + c1 * 8);
            __syncthreads();

            bf16x8 aF[4], bF[4];
            #pragma unroll
            for (int i = 0; i < 4; ++i) {
                int row = wm * 64 + i * 16 + l15;
                int ca  = row * 4 + (q ^ ((row >> 1) & 3));
                aF[i] = *(const bf16x8*)(sA + ca * 8);
                int nn = wn * 64 + i * 16 + l15;
                int cb = nn * 4 + (q ^ ((nn >> 1) & 3));
                bF[i] = *(const bf16x8*)(sW + cb * 8);
            }
            #pragma unroll
            for (int i = 0; i < 4; ++i)
                #pragma unroll
                for (int j = 0; j < 4; ++j)
                    acc[i][j] = __builtin_amdgcn_mfma_f32_16x16x32_bf16(aF[i], bF[j], acc[i][j], 0, 0, 0);
            __syncthreads();
        }
    }

    float bcol[4];
    #pragma unroll
    for (int j = 0; j < 4; ++j) bcol[j] = bias[wn * 64 + j * 16 + l15];
    #pragma unroll
    for (int i = 0; i < 4; ++i) {
        #pragma unroll
        for (int r = 0; r < 4; ++r) {
            int row = n0 + wm * 64 + i * 16 + q * 4 + r;
            if (row < N_NODES) {
                #pragma unroll
                for (int j = 0; j < 4; ++j) {
                    int col = wn * 64 + j * 16 + l15;
                    float v = acc[i][j][r] + bcol[j];
                    v = fmaxf(v, 0.f);
                    Cout[(size_t)row * DD + col] = f2b(v);
                }
            }
        }
    }
}

// ---------------- final FC: out = h @ fc_W + fc_b ----------------

__global__ void fc_kernel(const unsigned short* __restrict__ h, const float* __restrict__ fcW,
                          const float* __restrict__ fcb, float* __restrict__ out) {
    int n = blockIdx.x * blockDim.x + threadIdx.x;
    if (n >= N_NODES) return;
    const unsigned* hr = (const unsigned*)(h + (size_t)n * DD);
    float s0 = fcb[0], s1 = fcb[1];
    #pragma unroll 8
    for (int k = 0; k < 64; ++k) {
        unsigned v = hr[k];
        float h0 = __uint_as_float(v << 16);
        float h1 = __uint_as_float(v & 0xFFFF0000u);
        s0 += h0 * fcW[(2 * k) * 2]     + h1 * fcW[(2 * k + 1) * 2];
        s1 += h0 * fcW[(2 * k) * 2 + 1] + h1 * fcW[(2 * k + 1) * 2 + 1];
    }
    out[n * 2] = s0; out[n * 2 + 1] = s1;
}

// ---------------- launch ----------------

extern "C" void kernel_launch(void* const* d_in, const int* in_sizes, int n_in,
                              void* d_out, int out_size, void* d_ws, size_t ws_size,
                              hipStream_t stream) {
    const float* x    = (const float*)d_in[0];
    const int*   ei   = (const int*)d_in[1];
    const float* Wl   = (const float*)d_in[2];
    const float* Wr   = (const float*)d_in[3];
    const float* bl   = (const float*)d_in[4];
    const float* fcW  = (const float*)d_in[5];
    const float* fcb  = (const float*)d_in[6];
    float* out = (float*)d_out;

    const int* srcIdx = ei;
    const int* dstIdx = ei + N_EDGES;

    char* ws = (char*)d_ws;
    size_t off = 0;
    auto bump = [&](size_t bytes) { char* p = ws + off; off = (off + bytes + 255) & ~(size_t)255; return p; };
    int*   deg     = (int*)  bump(N_NODES * 4);
    int*   cursor  = (int*)  bump(N_NODES * 4);
    int*   offsets = (int*)  bump((N_NODES + 1) * 4);
    int*   bsum    = (int*)  bump(SCAN_BLOCKS * 4);
    float* deg_inv = (float*)bump(N_NODES * 4);
    int*   csr     = (int*)  bump(N_EDGES * 4);
    unsigned short* hx   = (unsigned short*)bump((size_t)N_NODES * DD * 2);
    unsigned short* hb0  = (unsigned short*)bump((size_t)N_NODES * DD * 2);
    unsigned short* hb1  = (unsigned short*)bump((size_t)N_NODES * DD * 2);
    unsigned short* agg  = (unsigned short*)bump((size_t)N_NODES * DD * 2);
    unsigned short* WT2  = (unsigned short*)bump((size_t)N_LAYERS * 128 * 256 * 2);
    (void)ws_size;

    zero_counts<<<(N_NODES + 255) / 256, 256, 0, stream>>>(deg, cursor);
    count_deg<<<(N_EDGES + 255) / 256, 256, 0, stream>>>(dstIdx, deg);
    block_sums<<<SCAN_BLOCKS, 256, 0, stream>>>(deg, bsum);
    scan_bsums<<<1, 256, 0, stream>>>(bsum, offsets);
    write_offsets<<<SCAN_BLOCKS, 256, 0, stream>>>(deg, bsum, offsets, deg_inv);
    fill_csr<<<(N_EDGES + 255) / 256, 256, 0, stream>>>(srcIdx, dstIdx, offsets, cursor, csr);
    x_to_bf16<<<(N_NODES * DD / 4 + 255) / 256, 256, 0, stream>>>(x, hx);
    prep_weights<<<(N_LAYERS * 128 * 256 + 255) / 256, 256, 0, stream>>>(Wl, Wr, WT2);

    const unsigned short* hin = hx;
    unsigned short* hbuf[2] = { hb0, hb1 };
    for (int l = 0; l < N_LAYERS; ++l) {
        aggregate<<<(N_NODES + 3) / 4, 256, 0, stream>>>(hin, offsets, csr, deg_inv, agg);
        unsigned short* hout = hbuf[l & 1];
        gemm_mfma<<<(N_NODES + 127) / 128, 256, 0, stream>>>(
            agg, hin, WT2 + (size_t)l * 128 * 256, bl + (size_t)l * DD, hout);
        hin = hout;
    }
    fc_kernel<<<(N_NODES + 255) / 256, 256, 0, stream>>>(hin, fcW, fcb, out);
}